// Round 7
// baseline (632.018 us; speedup 1.0000x reference)
//
#include <hip/hip_runtime.h>
#include <cstdint>
#include <cstddef>

#define T_TOK 4096
#define DM 1024
#define HS 4096
#define NE 8
#define MAXROWS 9216   // 8192 pairs + 8*128 padding worst case
#define MAXTILES 72    // MAXROWS/128

typedef __attribute__((ext_vector_type(8))) short short8;
typedef __attribute__((ext_vector_type(4))) float floatx4;

__device__ __forceinline__ unsigned short f2bf(float f) {
  union { float f; unsigned u; } v; v.f = f;
  unsigned r = (v.u + 0x7fffu + ((v.u >> 16) & 1u)) >> 16;
  return (unsigned short)r;
}

__device__ __forceinline__ void gload_lds16(const void* g, void* l) {
  __builtin_amdgcn_global_load_lds((const __attribute__((address_space(1))) void*)g,
                                   (__attribute__((address_space(3))) void*)l, 16, 0, 0);
}

// ---------------- small kernels ----------------

__global__ void k_cvt_init(const float* __restrict__ x, unsigned short* __restrict__ xb,
                           int* counts, int* cursor, unsigned* list) {
  int i = blockIdx.x * 256 + threadIdx.x;  // 4 elems per thread
  if (i < NE) { counts[i] = 0; cursor[i] = 0; }
  if (i < MAXROWS) list[i] = 0xFFFFFFFFu;
  float4 v = ((const float4*)x)[i];
  union { unsigned short us[4]; uint2 u2; } o;
  o.us[0] = f2bf(v.x); o.us[1] = f2bf(v.y); o.us[2] = f2bf(v.z); o.us[3] = f2bf(v.w);
  ((uint2*)xb)[i] = o.u2;
}

__global__ void k_route(const float* __restrict__ x, const float* __restrict__ rw,
                        const float* __restrict__ rb, const float* __restrict__ lw,
                        const float* __restrict__ lb, int* __restrict__ top_i,
                        float* __restrict__ top_p, int* __restrict__ counts) {
  int t = blockIdx.x * 4 + (threadIdx.x >> 6);
  int lane = threadIdx.x & 63;
  const float4* xt = (const float4*)(x + (size_t)t * DM);
  float4 xv[4];
#pragma unroll
  for (int j = 0; j < 4; j++) xv[j] = xt[lane * 4 + j];
  float dots[12];
#pragma unroll
  for (int r = 0; r < 12; r++) {
    const float4* wr = (const float4*)(r < 4 ? lw + r * DM : rw + (r - 4) * DM);
    float s = 0.f;
#pragma unroll
    for (int j = 0; j < 4; j++) {
      float4 w = wr[lane * 4 + j];
      s += xv[j].x * w.x + xv[j].y * w.y + xv[j].z * w.z + xv[j].w * w.w;
    }
#pragma unroll
    for (int o = 32; o > 0; o >>= 1) s += __shfl_xor(s, o, 64);
    dots[r] = s;
  }
  if (lane == 0) {
    float lp[4]; float m = -1e30f;
#pragma unroll
    for (int i = 0; i < 4; i++) { lp[i] = dots[i] + lb[i]; m = fmaxf(m, lp[i]); }
    float sum = 0.f;
#pragma unroll
    for (int i = 0; i < 4; i++) { lp[i] = expf(lp[i] - m); sum += lp[i]; }
#pragma unroll
    for (int i = 0; i < 4; i++) lp[i] /= sum;
    float ew[4];
    ew[0] = lp[0] + lp[1]; ew[1] = lp[1] + lp[2]; ew[2] = lp[2] + lp[3]; ew[3] = lp[3];
    float r8[8];
#pragma unroll
    for (int e = 0; e < 8; e++) r8[e] = dots[4 + e] + rb[e] + 0.1f * ew[e & 3];
    int e0 = 0;
#pragma unroll
    for (int e = 1; e < 8; e++) if (r8[e] > r8[e0]) e0 = e;
    int e1 = (e0 == 0) ? 1 : 0;
#pragma unroll
    for (int e = 0; e < 8; e++) if (e != e0 && r8[e] > r8[e1]) e1 = e;
    float tt = expf(r8[e1] - r8[e0]);
    float w0 = 1.f / (1.f + tt);
    float w1 = tt / (1.f + tt);
    top_i[t * 2] = e0; top_i[t * 2 + 1] = e1;
    top_p[t * 2] = w0; top_p[t * 2 + 1] = w1;
    atomicAdd(&counts[e0], 1); atomicAdd(&counts[e1], 1);
  }
}

__global__ void k_offsets(const int* counts, int* off) {
  if (threadIdx.x == 0) {
    int acc = 0;
    for (int e = 0; e < NE; e++) {
      off[e] = acc;
      int p = ((counts[e] + 127) >> 7) << 7;
      acc += p;
    }
    off[NE] = acc;
  }
}

__global__ void k_scatter(const int* __restrict__ top_i, const int* __restrict__ off,
                          int* cursor, unsigned* __restrict__ list) {
  int t = blockIdx.x * 256 + threadIdx.x;
  if (t >= T_TOK) return;
#pragma unroll
  for (int k = 0; k < 2; k++) {
    int e = top_i[t * 2 + k];
    int pos = atomicAdd(&cursor[e], 1);
    list[off[e] + pos] = (unsigned)(t * 2 + k);
  }
}

// transpose+convert: src f32 [e][K][N] -> dst bf16 [e][N][K]
__global__ void k_transpose_bf16(const float* __restrict__ src, unsigned short* __restrict__ dst,
                                 int K, int N) {
  __shared__ float tile[64][65];
  const float* s = src + (size_t)blockIdx.z * K * N;
  unsigned short* d = dst + (size_t)blockIdx.z * K * N;
  int n0 = blockIdx.x * 64, k0 = blockIdx.y * 64;
  int tr = threadIdx.x >> 4;          // 0..15
  int tc = (threadIdx.x & 15) * 4;    // 0,4,...,60
#pragma unroll
  for (int j = 0; j < 4; j++) {
    int row = tr + j * 16;
    float4 v = *(const float4*)&s[(size_t)(k0 + row) * N + n0 + tc];
    tile[row][tc + 0] = v.x; tile[row][tc + 1] = v.y;
    tile[row][tc + 2] = v.z; tile[row][tc + 3] = v.w;
  }
  __syncthreads();
#pragma unroll
  for (int j = 0; j < 4; j++) {
    int n = tr + j * 16;
    union { unsigned short us[4]; uint2 u2; } o;
#pragma unroll
    for (int i = 0; i < 4; i++) o.us[i] = f2bf(tile[tc + i][n]);
    *(uint2*)&d[(size_t)(n0 + n) * K + k0 + tc] = o.u2;
  }
}

__global__ void k_init_out(const int* __restrict__ top_i, const float* __restrict__ top_p,
                           const float* __restrict__ b2, float* __restrict__ out) {
  int i = blockIdx.x * 256 + threadIdx.x;
  int t = i >> 10, d = i & 1023;
  int e0 = top_i[t * 2], e1 = top_i[t * 2 + 1];
  out[i] = top_p[t * 2] * b2[e0 * DM + d] + top_p[t * 2 + 1] * b2[e1 * DM + d];
}

// ---------------- grouped GEMM (round-2 proven structure) ----------------
template <int MODE>
__global__ __launch_bounds__(256, 4) void k_gemm(
    const unsigned short* __restrict__ Abase,
    const unsigned short* __restrict__ Wt,   // [E][N][K] bf16
    const int* __restrict__ off, const unsigned* __restrict__ list,
    const float* __restrict__ bias, const float* __restrict__ top_p,
    unsigned short* __restrict__ Hout, float* __restrict__ out,
    int K, int N) {
  int nx = gridDim.x;
  int flat = blockIdx.y * nx + blockIdx.x;
  int cpx = (nx * gridDim.y) >> 3;
  int swz = (flat & 7) * cpx + (flat >> 3);
  int n0 = (swz % nx) * 128;
  int r0 = (swz / nx) * 128;

  int total = off[NE];
  if (r0 >= total) return;
  int e = 0;
  while (r0 >= off[e + 1]) ++e;

  __shared__ __align__(16) unsigned short lA[2][128 * 32];
  __shared__ __align__(16) unsigned short lB[2][128 * 32];
  __shared__ float sP[128];
  __shared__ int sTok[128];

  int tid = threadIdx.x;
  int srow = tid >> 2;
  int key_s = (srow >> 1) & 3;
  int koff_src = ((tid & 3) ^ key_s) * 8;
  int kdst = (tid & 3) * 8;

  const unsigned short* srcA[2];
#pragma unroll
  for (int c = 0; c < 2; c++) {
    int row = c * 64 + srow;
    size_t arow;
    if (MODE == 0) {
      unsigned pair = list[r0 + row];
      arow = (pair == 0xFFFFFFFFu) ? 0 : (size_t)(pair >> 1);
    } else {
      arow = (size_t)(r0 + row);
    }
    srcA[c] = Abase + arow * K + koff_src;
  }
  const unsigned short* srcB[2];
#pragma unroll
  for (int c = 0; c < 2; c++)
    srcB[c] = Wt + ((size_t)e * N + n0 + c * 64 + srow) * K + koff_src;

  if (MODE == 1 && tid < 128) {
    unsigned pair = list[r0 + tid];
    if (pair == 0xFFFFFFFFu) { sTok[tid] = -1; sP[tid] = 0.f; }
    else { sTok[tid] = (int)(pair >> 1); sP[tid] = top_p[pair]; }
  }

  floatx4 acc[4][4] = {};
  int lane = tid & 63;
  int w = tid >> 6;
  int wm = w >> 1, wn = w & 1;
  int lr = lane & 15, kq = lane >> 4;
  int kx = kq ^ ((lr >> 1) & 3);

#define STAGE(BUF, KK)                                                        \
  do {                                                                        \
    _Pragma("unroll")                                                         \
    for (int c = 0; c < 2; c++) {                                             \
      gload_lds16(srcA[c] + (KK), &lA[BUF][(c * 64 + srow) * 32 + kdst]);     \
      gload_lds16(srcB[c] + (KK), &lB[BUF][(c * 64 + srow) * 32 + kdst]);     \
    }                                                                         \
  } while (0)

  STAGE(0, 0);
  __syncthreads();

  int cur = 0;
  for (int k0 = 0; k0 < K; k0 += 32) {
    if (k0 + 32 < K) STAGE(cur ^ 1, k0 + 32);
    const short8* pA = (const short8*)lA[cur];
    const short8* pB = (const short8*)lB[cur];
    short8 a[4], b[4];
#pragma unroll
    for (int i = 0; i < 4; i++) a[i] = pA[(wm * 64 + i * 16 + lr) * 4 + kx];
#pragma unroll
    for (int j = 0; j < 4; j++) b[j] = pB[(wn * 64 + j * 16 + lr) * 4 + kx];
#pragma unroll
    for (int i = 0; i < 4; i++)
#pragma unroll
      for (int j = 0; j < 4; j++)
        acc[i][j] = __builtin_amdgcn_mfma_f32_16x16x32_bf16(a[i], b[j], acc[i][j], 0, 0, 0);
    __syncthreads();
    cur ^= 1;
  }
#undef STAGE

  int rbase = wm * 64 + kq * 4;
  int cbase = wn * 64 + lr;
  if (MODE == 0) {
#pragma unroll
    for (int i = 0; i < 4; i++)
#pragma unroll
      for (int j = 0; j < 4; j++)
#pragma unroll
        for (int g = 0; g < 4; g++) {
          int row = rbase + i * 16 + g;
          int col = cbase + j * 16;
          float v = acc[i][j][g] + bias[e * N + n0 + col];
          float u = v * (0.7978845608f + 0.0356774081f * v * v);
          float gl = v / (1.f + __expf(-2.f * u));
          Hout[(size_t)(r0 + row) * (size_t)N + n0 + col] = f2bf(gl);
        }
  } else {
#pragma unroll
    for (int i = 0; i < 4; i++)
#pragma unroll
      for (int j = 0; j < 4; j++)
#pragma unroll
        for (int g = 0; g < 4; g++) {
          int row = rbase + i * 16 + g;
          int col = cbase + j * 16;
          int tok = sTok[row];
          if (tok >= 0)
            atomicAdd(&out[(size_t)tok * DM + n0 + col], sP[row] * acc[i][j][g]);
        }
  }
}

// ---------------- diagnostic ablations (GEMM1-shaped; results -> scratch) ----------------
// Staging path ONLY: same gather + gload_lds + barrier cadence, no ds_read/MFMA.
__global__ __launch_bounds__(256, 4) void k_abl_stage(
    const unsigned short* __restrict__ Abase, const unsigned short* __restrict__ Wt,
    const int* __restrict__ off, const unsigned* __restrict__ list,
    float* __restrict__ scratch, int K, int N) {
  int nx = gridDim.x;
  int flat = blockIdx.y * nx + blockIdx.x;
  int cpx = (nx * gridDim.y) >> 3;
  int swz = (flat & 7) * cpx + (flat >> 3);
  int n0 = (swz % nx) * 128;
  int r0 = (swz / nx) * 128;
  int total = off[NE];
  if (r0 >= total) return;
  int e = 0;
  while (r0 >= off[e + 1]) ++e;

  __shared__ __align__(16) unsigned short lA[2][128 * 32];
  __shared__ __align__(16) unsigned short lB[2][128 * 32];

  int tid = threadIdx.x;
  int srow = tid >> 2;
  int key_s = (srow >> 1) & 3;
  int koff_src = ((tid & 3) ^ key_s) * 8;
  int kdst = (tid & 3) * 8;

  const unsigned short* srcA[2];
#pragma unroll
  for (int c = 0; c < 2; c++) {
    unsigned pair = list[r0 + c * 64 + srow];
    size_t arow = (pair == 0xFFFFFFFFu) ? 0 : (size_t)(pair >> 1);
    srcA[c] = Abase + arow * K + koff_src;
  }
  const unsigned short* srcB[2];
#pragma unroll
  for (int c = 0; c < 2; c++)
    srcB[c] = Wt + ((size_t)e * N + n0 + c * 64 + srow) * K + koff_src;

#define STG(BUF, KK)                                                          \
  do {                                                                        \
    _Pragma("unroll")                                                         \
    for (int c = 0; c < 2; c++) {                                             \
      gload_lds16(srcA[c] + (KK), &lA[BUF][(c * 64 + srow) * 32 + kdst]);     \
      gload_lds16(srcB[c] + (KK), &lB[BUF][(c * 64 + srow) * 32 + kdst]);     \
    }                                                                         \
  } while (0)
  STG(0, 0);
  __syncthreads();
  int cur = 0;
  for (int k0 = 0; k0 < K; k0 += 32) {
    if (k0 + 32 < K) STG(cur ^ 1, k0 + 32);
    __syncthreads();
    cur ^= 1;
  }
#undef STG
  float s = (float)lA[0][tid] + (float)lB[0][tid] + (float)lA[1][tid] + (float)lB[1][tid];
  scratch[(size_t)flat * 256 + tid] = s;
}

// LDS->MFMA pipeline ONLY: stage both buffers once, then full ds_read+MFMA loop.
__global__ __launch_bounds__(256, 4) void k_abl_mfma(
    const unsigned short* __restrict__ Abase, const unsigned short* __restrict__ Wt,
    const int* __restrict__ off, const unsigned* __restrict__ list,
    float* __restrict__ scratch, int K, int N) {
  int nx = gridDim.x;
  int flat = blockIdx.y * nx + blockIdx.x;
  int cpx = (nx * gridDim.y) >> 3;
  int swz = (flat & 7) * cpx + (flat >> 3);
  int n0 = (swz % nx) * 128;
  int r0 = (swz / nx) * 128;
  int total = off[NE];
  if (r0 >= total) return;
  int e = 0;
  while (r0 >= off[e + 1]) ++e;

  __shared__ __align__(16) unsigned short lA[2][128 * 32];
  __shared__ __align__(16) unsigned short lB[2][128 * 32];

  int tid = threadIdx.x;
  int srow = tid >> 2;
  int key_s = (srow >> 1) & 3;
  int koff_src = ((tid & 3) ^ key_s) * 8;
  int kdst = (tid & 3) * 8;

  const unsigned short* srcA[2];
#pragma unroll
  for (int c = 0; c < 2; c++) {
    unsigned pair = list[r0 + c * 64 + srow];
    size_t arow = (pair == 0xFFFFFFFFu) ? 0 : (size_t)(pair >> 1);
    srcA[c] = Abase + arow * K + koff_src;
  }
  const unsigned short* srcB[2];
#pragma unroll
  for (int c = 0; c < 2; c++)
    srcB[c] = Wt + ((size_t)e * N + n0 + c * 64 + srow) * K + koff_src;

#pragma unroll
  for (int c = 0; c < 2; c++) {
    gload_lds16(srcA[c], &lA[0][(c * 64 + srow) * 32 + kdst]);
    gload_lds16(srcB[c], &lB[0][(c * 64 + srow) * 32 + kdst]);
    gload_lds16(srcA[c] + 32, &lA[1][(c * 64 + srow) * 32 + kdst]);
    gload_lds16(srcB[c] + 32, &lB[1][(c * 64 + srow) * 32 + kdst]);
  }
  __syncthreads();

  floatx4 acc[4][4] = {};
  int lane = tid & 63;
  int w = tid >> 6;
  int wm = w >> 1, wn = w & 1;
  int lr = lane & 15, kq = lane >> 4;
  int kx = kq ^ ((lr >> 1) & 3);

  for (int k0 = 0; k0 < K; k0 += 32) {
    int cur = (k0 >> 5) & 1;
    const short8* pA = (const short8*)lA[cur];
    const short8* pB = (const short8*)lB[cur];
    short8 a[4], b[4];
#pragma unroll
    for (int i = 0; i < 4; i++) a[i] = pA[(wm * 64 + i * 16 + lr) * 4 + kx];
#pragma unroll
    for (int j = 0; j < 4; j++) b[j] = pB[(wn * 64 + j * 16 + lr) * 4 + kx];
#pragma unroll
    for (int i = 0; i < 4; i++)
#pragma unroll
      for (int j = 0; j < 4; j++)
        acc[i][j] = __builtin_amdgcn_mfma_f32_16x16x32_bf16(a[i], b[j], acc[i][j], 0, 0, 0);
    __syncthreads();
  }
  float s = 0.f;
#pragma unroll
  for (int i = 0; i < 4; i++)
#pragma unroll
    for (int j = 0; j < 4; j++)
#pragma unroll
      for (int g = 0; g < 4; g++) s += acc[i][j][g];
  scratch[(size_t)flat * 256 + tid] = s;
}

// ---------------- launch ----------------

extern "C" void kernel_launch(void* const* d_in, const int* in_sizes, int n_in,
                              void* d_out, int out_size, void* d_ws, size_t ws_size,
                              hipStream_t stream) {
  const float* x  = (const float*)d_in[0];
  const float* rw = (const float*)d_in[1];
  const float* rb = (const float*)d_in[2];
  const float* lw = (const float*)d_in[3];
  const float* lb = (const float*)d_in[4];
  const float* w1 = (const float*)d_in[5];
  const float* b1 = (const float*)d_in[6];
  const float* w2 = (const float*)d_in[7];
  const float* b2 = (const float*)d_in[8];
  float* out = (float*)d_out;
  char* ws = (char*)d_ws;

  int* counts = (int*)ws;
  int* cursor = (int*)(ws + 32);
  int* off    = (int*)(ws + 64);
  int* top_i  = (int*)(ws + 128);
  float* top_p = (float*)(ws + 128 + 32768);
  unsigned* list = (unsigned*)(ws + 65792);
  unsigned short* xb = (unsigned short*)(ws + 102912);
  unsigned short* wt = (unsigned short*)(ws + 102912 + 8388608);            // 64 MB shared w1t/w2t
  unsigned short* h  = (unsigned short*)(ws + 102912 + 8388608 + 67108864); // 72 MB
  float* scratch = (float*)h;  // h is dead after k_gemm<1>; ablations write here

  k_cvt_init<<<dim3(T_TOK * DM / 4 / 256), dim3(256), 0, stream>>>(x, xb, counts, cursor, list);
  k_route<<<dim3(T_TOK / 4), dim3(256), 0, stream>>>(x, rw, rb, lw, lb, top_i, top_p, counts);
  k_offsets<<<dim3(1), dim3(64), 0, stream>>>(counts, off);
  k_scatter<<<dim3(T_TOK / 256), dim3(256), 0, stream>>>(top_i, off, cursor, list);
  k_transpose_bf16<<<dim3(HS / 64, DM / 64, NE), dim3(256), 0, stream>>>(w1, wt, DM, HS);
  k_init_out<<<dim3(T_TOK * DM / 256), dim3(256), 0, stream>>>(top_i, top_p, b2, out);
  k_gemm<0><<<dim3(HS / 128, MAXTILES), dim3(256), 0, stream>>>(
      xb, wt, off, list, b1, top_p, h, nullptr, DM, HS);
  k_transpose_bf16<<<dim3(DM / 64, HS / 64, NE), dim3(256), 0, stream>>>(w2, wt, HS, DM);
  k_gemm<1><<<dim3(DM / 128, MAXTILES), dim3(256), 0, stream>>>(
      h, wt, off, list, nullptr, top_p, nullptr, out, HS, DM);
  // ---- diagnostic ablations (after real pipeline; overwrite dead h region) ----
  k_abl_stage<<<dim3(HS / 128, MAXTILES), dim3(256), 0, stream>>>(
      xb, wt, off, list, scratch, DM, HS);
  k_abl_mfma<<<dim3(HS / 128, MAXTILES), dim3(256), 0, stream>>>(
      xb, wt, off, list, scratch, DM, HS);
}

// Round 8
// 583.915 us; speedup vs baseline: 1.0824x; 1.0824x over previous
//
#include <hip/hip_runtime.h>
#include <cstdint>
#include <cstddef>

#define T_TOK 4096
#define DM 1024
#define HS 4096
#define NE 8
#define MAXROWS 9216   // 8192 pairs + 8*128 padding worst case
#define MAXTILES 72    // MAXROWS/128

typedef __attribute__((ext_vector_type(8))) short short8;
typedef __attribute__((ext_vector_type(4))) float floatx4;

__device__ __forceinline__ unsigned short f2bf(float f) {
  union { float f; unsigned u; } v; v.f = f;
  unsigned r = (v.u + 0x7fffu + ((v.u >> 16) & 1u)) >> 16;
  return (unsigned short)r;
}

__device__ __forceinline__ void gload_lds16(const void* g, void* l) {
  __builtin_amdgcn_global_load_lds((const __attribute__((address_space(1))) void*)g,
                                   (__attribute__((address_space(3))) void*)l, 16, 0, 0);
}

// ---------------- fused cvt(x->bf16) + routing ----------------
// grid 1024 blocks x 256 thr; block b handles tokens 4b..4b+3.
__global__ void k_cvt_route(const float* __restrict__ x, unsigned short* __restrict__ xb,
                            const float* __restrict__ rw, const float* __restrict__ rb,
                            const float* __restrict__ lw, const float* __restrict__ lb,
                            int* __restrict__ top_i, float* __restrict__ top_p,
                            int* __restrict__ counts) {
  // --- cvt part: 1024 float4 per block ---
#pragma unroll
  for (int j = 0; j < 4; j++) {
    int i = blockIdx.x * 1024 + j * 256 + threadIdx.x;
    float4 v = ((const float4*)x)[i];
    union { unsigned short us[4]; uint2 u2; } o;
    o.us[0] = f2bf(v.x); o.us[1] = f2bf(v.y); o.us[2] = f2bf(v.z); o.us[3] = f2bf(v.w);
    ((uint2*)xb)[i] = o.u2;
  }
  // --- route part: 1 token per wave ---
  int t = blockIdx.x * 4 + (threadIdx.x >> 6);
  int lane = threadIdx.x & 63;
  const float4* xt = (const float4*)(x + (size_t)t * DM);
  float4 xv[4];
#pragma unroll
  for (int j = 0; j < 4; j++) xv[j] = xt[lane * 4 + j];
  float dots[12];
#pragma unroll
  for (int r = 0; r < 12; r++) {
    const float4* wr = (const float4*)(r < 4 ? lw + r * DM : rw + (r - 4) * DM);
    float s = 0.f;
#pragma unroll
    for (int j = 0; j < 4; j++) {
      float4 w = wr[lane * 4 + j];
      s += xv[j].x * w.x + xv[j].y * w.y + xv[j].z * w.z + xv[j].w * w.w;
    }
#pragma unroll
    for (int o = 32; o > 0; o >>= 1) s += __shfl_xor(s, o, 64);
    dots[r] = s;
  }
  if (lane == 0) {
    float lp[4]; float m = -1e30f;
#pragma unroll
    for (int i = 0; i < 4; i++) { lp[i] = dots[i] + lb[i]; m = fmaxf(m, lp[i]); }
    float sum = 0.f;
#pragma unroll
    for (int i = 0; i < 4; i++) { lp[i] = expf(lp[i] - m); sum += lp[i]; }
#pragma unroll
    for (int i = 0; i < 4; i++) lp[i] /= sum;
    float ew[4];
    ew[0] = lp[0] + lp[1]; ew[1] = lp[1] + lp[2]; ew[2] = lp[2] + lp[3]; ew[3] = lp[3];
    float r8[8];
#pragma unroll
    for (int e = 0; e < 8; e++) r8[e] = dots[4 + e] + rb[e] + 0.1f * ew[e & 3];
    int e0 = 0;
#pragma unroll
    for (int e = 1; e < 8; e++) if (r8[e] > r8[e0]) e0 = e;
    int e1 = (e0 == 0) ? 1 : 0;
#pragma unroll
    for (int e = 0; e < 8; e++) if (e != e0 && r8[e] > r8[e1]) e1 = e;
    float tt = expf(r8[e1] - r8[e0]);
    float w0 = 1.f / (1.f + tt);
    float w1 = tt / (1.f + tt);
    top_i[t * 2] = e0; top_i[t * 2 + 1] = e1;
    top_p[t * 2] = w0; top_p[t * 2 + 1] = w1;
    atomicAdd(&counts[e0], 1); atomicAdd(&counts[e1], 1);
  }
}

// ---------------- fused offsets + scatter (single block) ----------------
__global__ void k_offscatter(const int* __restrict__ counts, int* __restrict__ off,
                             const int* __restrict__ top_i, int* cursor,
                             unsigned* __restrict__ list) {
  if (threadIdx.x == 0) {
    int acc = 0;
    for (int e = 0; e < NE; e++) {
      off[e] = acc;
      acc += ((counts[e] + 127) >> 7) << 7;
    }
    off[NE] = acc;
  }
  __syncthreads();
  for (int t = threadIdx.x; t < T_TOK; t += 1024) {
#pragma unroll
    for (int k = 0; k < 2; k++) {
      int e = top_i[t * 2 + k];
      int pos = atomicAdd(&cursor[e], 1);
      list[off[e] + pos] = (unsigned)(t * 2 + k);
    }
  }
}

// transpose+convert: src f32 [e][K][N] -> dst bf16 [e][N][K]
__global__ void k_transpose_bf16(const float* __restrict__ src, unsigned short* __restrict__ dst,
                                 int K, int N) {
  __shared__ float tile[64][65];
  const float* s = src + (size_t)blockIdx.z * K * N;
  unsigned short* d = dst + (size_t)blockIdx.z * K * N;
  int n0 = blockIdx.x * 64, k0 = blockIdx.y * 64;
  int tr = threadIdx.x >> 4;          // 0..15
  int tc = (threadIdx.x & 15) * 4;    // 0,4,...,60
#pragma unroll
  for (int j = 0; j < 4; j++) {
    int row = tr + j * 16;
    float4 v = *(const float4*)&s[(size_t)(k0 + row) * N + n0 + tc];
    tile[row][tc + 0] = v.x; tile[row][tc + 1] = v.y;
    tile[row][tc + 2] = v.z; tile[row][tc + 3] = v.w;
  }
  __syncthreads();
#pragma unroll
  for (int j = 0; j < 4; j++) {
    int n = tr + j * 16;
    union { unsigned short us[4]; uint2 u2; } o;
#pragma unroll
    for (int i = 0; i < 4; i++) o.us[i] = f2bf(tile[tc + i][n]);
    *(uint2*)&d[(size_t)(n0 + n) * K + k0 + tc] = o.u2;
  }
}

__global__ void k_init_out(const int* __restrict__ top_i, const float* __restrict__ top_p,
                           const float* __restrict__ b2, float* __restrict__ out) {
  int i = blockIdx.x * 256 + threadIdx.x;
  int t = i >> 10, d = i & 1023;
  int e0 = top_i[t * 2], e1 = top_i[t * 2 + 1];
  out[i] = top_p[t * 2] * b2[e0 * DM + d] + top_p[t * 2 + 1] * b2[e1 * DM + d];
}

// ---------------- GEMM1: h = gelu(xg @ w1t^T + b1) ----------------
// A-DIRECT: xb is L2-resident (8 MB); A fragments are read straight from
// global into registers (per-lane gathered row pointers; lanes kq=0..3 of a
// row form one contiguous 64B segment). Only B goes through LDS -> per-step
// LDS traffic halves (48KB -> 24KB per block): attacks the measured LDS-port
// ceiling (~1225 cy/step at 4 blocks/CU).
__global__ __launch_bounds__(256, 4) void k_gemm1(
    const unsigned short* __restrict__ Abase,   // xb bf16 [T][DM]
    const unsigned short* __restrict__ Wt,      // w1t bf16 [E][HS][DM]
    const int* __restrict__ off, const unsigned* __restrict__ list,
    const float* __restrict__ bias, unsigned short* __restrict__ Hout) {
  const int K = DM, N = HS;
  int nx = gridDim.x;
  int flat = blockIdx.y * nx + blockIdx.x;
  int cpx = (nx * gridDim.y) >> 3;
  int swz = (flat & 7) * cpx + (flat >> 3);
  int n0 = (swz % nx) * 128;
  int r0 = (swz / nx) * 128;

  int total = off[NE];
  if (r0 >= total) return;
  int e = 0;
  while (r0 >= off[e + 1]) ++e;

  __shared__ __align__(16) unsigned short lB[2][128 * 32];

  int tid = threadIdx.x;
  int srow = tid >> 2;
  int key_s = (srow >> 1) & 3;
  int koff_src = ((tid & 3) ^ key_s) * 8;
  int kdst = (tid & 3) * 8;

  const unsigned short* srcB[2];
#pragma unroll
  for (int c = 0; c < 2; c++)
    srcB[c] = Wt + ((size_t)e * N + n0 + c * 64 + srow) * K + koff_src;

  int lane = tid & 63;
  int w = tid >> 6;
  int wm = w >> 1, wn = w & 1;
  int lr = lane & 15, kq = lane >> 4;
  int kx = kq ^ ((lr >> 1) & 3);

  // per-lane A row offsets (4 m-fragments), gathered once
  unsigned aoff[4];
#pragma unroll
  for (int i = 0; i < 4; i++) {
    int row = r0 + wm * 64 + i * 16 + lr;
    unsigned pair = list[row];
    unsigned arow = (pair == 0xFFFFFFFFu) ? 0u : (pair >> 1);
    aoff[i] = arow * (unsigned)K + (unsigned)(kq * 8);
  }

  floatx4 acc[4][4] = {};

#define STAGEB(BUF, KK)                                                       \
  do {                                                                        \
    _Pragma("unroll")                                                         \
    for (int c = 0; c < 2; c++)                                               \
      gload_lds16(srcB[c] + (KK), &lB[BUF][(c * 64 + srow) * 32 + kdst]);     \
  } while (0)

  STAGEB(0, 0);
  __syncthreads();

  int cur = 0;
  for (int k0 = 0; k0 < K; k0 += 32) {
    if (k0 + 32 < K) STAGEB(cur ^ 1, k0 + 32);
    const short8* pB = (const short8*)lB[cur];
    short8 a[4], b[4];
#pragma unroll
    for (int i = 0; i < 4; i++)
      a[i] = *(const short8*)(Abase + aoff[i] + k0);   // global -> reg, no LDS
#pragma unroll
    for (int j = 0; j < 4; j++) b[j] = pB[(wn * 64 + j * 16 + lr) * 4 + kx];
#pragma unroll
    for (int i = 0; i < 4; i++)
#pragma unroll
      for (int j = 0; j < 4; j++)
        acc[i][j] = __builtin_amdgcn_mfma_f32_16x16x32_bf16(a[i], b[j], acc[i][j], 0, 0, 0);
    __syncthreads();
    cur ^= 1;
  }
#undef STAGEB

  int rbase = wm * 64 + kq * 4;
  int cbase = wn * 64 + lr;
#pragma unroll
  for (int i = 0; i < 4; i++)
#pragma unroll
    for (int j = 0; j < 4; j++)
#pragma unroll
      for (int g = 0; g < 4; g++) {
        int row = rbase + i * 16 + g;
        int col = cbase + j * 16;
        float v = acc[i][j][g] + bias[e * N + n0 + col];
        float u = v * (0.7978845608f + 0.0356774081f * v * v);
        float gl = v / (1.f + __expf(-2.f * u));
        Hout[(size_t)(r0 + row) * (size_t)N + n0 + col] = f2bf(gl);
      }
}

// ---------------- GEMM2: out += p * (h @ w2t^T)  (round-7 proven) ----------------
__global__ __launch_bounds__(256, 4) void k_gemm2(
    const unsigned short* __restrict__ Abase,   // h bf16 [rows][HS]
    const unsigned short* __restrict__ Wt,      // w2t bf16 [E][DM][HS]
    const int* __restrict__ off, const unsigned* __restrict__ list,
    const float* __restrict__ top_p, float* __restrict__ out) {
  const int K = HS, N = DM;
  int nx = gridDim.x;
  int flat = blockIdx.y * nx + blockIdx.x;
  int cpx = (nx * gridDim.y) >> 3;
  int swz = (flat & 7) * cpx + (flat >> 3);
  int n0 = (swz % nx) * 128;
  int r0 = (swz / nx) * 128;

  int total = off[NE];
  if (r0 >= total) return;
  int e = 0;
  while (r0 >= off[e + 1]) ++e;

  __shared__ __align__(16) unsigned short lA[2][128 * 32];
  __shared__ __align__(16) unsigned short lB[2][128 * 32];
  __shared__ float sP[128];
  __shared__ int sTok[128];

  int tid = threadIdx.x;
  int srow = tid >> 2;
  int key_s = (srow >> 1) & 3;
  int koff_src = ((tid & 3) ^ key_s) * 8;
  int kdst = (tid & 3) * 8;

  const unsigned short* srcA[2];
#pragma unroll
  for (int c = 0; c < 2; c++)
    srcA[c] = Abase + (size_t)(r0 + c * 64 + srow) * K + koff_src;
  const unsigned short* srcB[2];
#pragma unroll
  for (int c = 0; c < 2; c++)
    srcB[c] = Wt + ((size_t)e * N + n0 + c * 64 + srow) * K + koff_src;

  if (tid < 128) {
    unsigned pair = list[r0 + tid];
    if (pair == 0xFFFFFFFFu) { sTok[tid] = -1; sP[tid] = 0.f; }
    else { sTok[tid] = (int)(pair >> 1); sP[tid] = top_p[pair]; }
  }

  floatx4 acc[4][4] = {};
  int lane = tid & 63;
  int w = tid >> 6;
  int wm = w >> 1, wn = w & 1;
  int lr = lane & 15, kq = lane >> 4;
  int kx = kq ^ ((lr >> 1) & 3);

#define STAGE(BUF, KK)                                                        \
  do {                                                                        \
    _Pragma("unroll")                                                         \
    for (int c = 0; c < 2; c++) {                                             \
      gload_lds16(srcA[c] + (KK), &lA[BUF][(c * 64 + srow) * 32 + kdst]);     \
      gload_lds16(srcB[c] + (KK), &lB[BUF][(c * 64 + srow) * 32 + kdst]);     \
    }                                                                         \
  } while (0)

  STAGE(0, 0);
  __syncthreads();

  int cur = 0;
  for (int k0 = 0; k0 < K; k0 += 32) {
    if (k0 + 32 < K) STAGE(cur ^ 1, k0 + 32);
    const short8* pA = (const short8*)lA[cur];
    const short8* pB = (const short8*)lB[cur];
    short8 a[4], b[4];
#pragma unroll
    for (int i = 0; i < 4; i++) a[i] = pA[(wm * 64 + i * 16 + lr) * 4 + kx];
#pragma unroll
    for (int j = 0; j < 4; j++) b[j] = pB[(wn * 64 + j * 16 + lr) * 4 + kx];
#pragma unroll
    for (int i = 0; i < 4; i++)
#pragma unroll
      for (int j = 0; j < 4; j++)
        acc[i][j] = __builtin_amdgcn_mfma_f32_16x16x32_bf16(a[i], b[j], acc[i][j], 0, 0, 0);
    __syncthreads();
    cur ^= 1;
  }
#undef STAGE

  int rbase = wm * 64 + kq * 4;
  int cbase = wn * 64 + lr;
#pragma unroll
  for (int i = 0; i < 4; i++)
#pragma unroll
    for (int j = 0; j < 4; j++)
#pragma unroll
      for (int g = 0; g < 4; g++) {
        int row = rbase + i * 16 + g;
        int col = cbase + j * 16;
        int tok = sTok[row];
        if (tok >= 0)
          atomicAdd(&out[(size_t)tok * DM + n0 + col], sP[row] * acc[i][j][g]);
      }
}

// ---------------- launch ----------------

extern "C" void kernel_launch(void* const* d_in, const int* in_sizes, int n_in,
                              void* d_out, int out_size, void* d_ws, size_t ws_size,
                              hipStream_t stream) {
  const float* x  = (const float*)d_in[0];
  const float* rw = (const float*)d_in[1];
  const float* rb = (const float*)d_in[2];
  const float* lw = (const float*)d_in[3];
  const float* lb = (const float*)d_in[4];
  const float* w1 = (const float*)d_in[5];
  const float* b1 = (const float*)d_in[6];
  const float* w2 = (const float*)d_in[7];
  const float* b2 = (const float*)d_in[8];
  float* out = (float*)d_out;
  char* ws = (char*)d_ws;

  int* counts = (int*)ws;
  int* cursor = (int*)(ws + 32);
  int* off    = (int*)(ws + 64);
  int* top_i  = (int*)(ws + 128);
  float* top_p = (float*)(ws + 128 + 32768);
  unsigned* list = (unsigned*)(ws + 65792);
  unsigned short* xb = (unsigned short*)(ws + 102912);
  unsigned short* wt = (unsigned short*)(ws + 102912 + 8388608);            // 64 MB shared w1t/w2t
  unsigned short* h  = (unsigned short*)(ws + 102912 + 8388608 + 67108864); // 72 MB

  hipMemsetAsync(ws, 0, 128, stream);                    // counts+cursor+off
  hipMemsetAsync(list, 0xFF, MAXROWS * 4, stream);       // sentinel list
  k_cvt_route<<<dim3(T_TOK / 4), dim3(256), 0, stream>>>(
      x, xb, rw, rb, lw, lb, top_i, top_p, counts);
  k_offscatter<<<dim3(1), dim3(1024), 0, stream>>>(counts, off, top_i, cursor, list);
  k_transpose_bf16<<<dim3(HS / 64, DM / 64, NE), dim3(256), 0, stream>>>(w1, wt, DM, HS);
  k_init_out<<<dim3(T_TOK * DM / 256), dim3(256), 0, stream>>>(top_i, top_p, b2, out);
  k_gemm1<<<dim3(HS / 128, MAXTILES), dim3(256), 0, stream>>>(
      xb, wt, off, list, b1, h);
  k_transpose_bf16<<<dim3(DM / 64, HS / 64, NE), dim3(256), 0, stream>>>(w2, wt, HS, DM);
  k_gemm2<<<dim3(DM / 128, MAXTILES), dim3(256), 0, stream>>>(
      h, wt, off, list, top_p, out);
}

// Round 9
// 538.937 us; speedup vs baseline: 1.1727x; 1.0835x over previous
//
#include <hip/hip_runtime.h>
#include <cstdint>
#include <cstddef>

#define T_TOK 4096
#define DM 1024
#define HS 4096
#define NE 8
#define MAXROWS 10240  // 8192 pairs + 8*256 padding worst case
#define MT1 40         // 256-row tiles (GEMM1)
#define MT2 80         // 128-row tiles (GEMM2)

typedef __attribute__((ext_vector_type(8))) short short8;
typedef __attribute__((ext_vector_type(4))) float floatx4;

__device__ __forceinline__ unsigned short f2bf(float f) {
  union { float f; unsigned u; } v; v.f = f;
  unsigned r = (v.u + 0x7fffu + ((v.u >> 16) & 1u)) >> 16;
  return (unsigned short)r;
}

__device__ __forceinline__ void gload_lds16(const void* g, void* l) {
  __builtin_amdgcn_global_load_lds((const __attribute__((address_space(1))) void*)g,
                                   (__attribute__((address_space(3))) void*)l, 16, 0, 0);
}

// ---------------- fused cvt(x->bf16) + routing ----------------
__global__ void k_cvt_route(const float* __restrict__ x, unsigned short* __restrict__ xb,
                            const float* __restrict__ rw, const float* __restrict__ rb,
                            const float* __restrict__ lw, const float* __restrict__ lb,
                            int* __restrict__ top_i, float* __restrict__ top_p,
                            int* __restrict__ counts) {
#pragma unroll
  for (int j = 0; j < 4; j++) {
    int i = blockIdx.x * 1024 + j * 256 + threadIdx.x;
    float4 v = ((const float4*)x)[i];
    union { unsigned short us[4]; uint2 u2; } o;
    o.us[0] = f2bf(v.x); o.us[1] = f2bf(v.y); o.us[2] = f2bf(v.z); o.us[3] = f2bf(v.w);
    ((uint2*)xb)[i] = o.u2;
  }
  int t = blockIdx.x * 4 + (threadIdx.x >> 6);
  int lane = threadIdx.x & 63;
  const float4* xt = (const float4*)(x + (size_t)t * DM);
  float4 xv[4];
#pragma unroll
  for (int j = 0; j < 4; j++) xv[j] = xt[lane * 4 + j];
  float dots[12];
#pragma unroll
  for (int r = 0; r < 12; r++) {
    const float4* wr = (const float4*)(r < 4 ? lw + r * DM : rw + (r - 4) * DM);
    float s = 0.f;
#pragma unroll
    for (int j = 0; j < 4; j++) {
      float4 w = wr[lane * 4 + j];
      s += xv[j].x * w.x + xv[j].y * w.y + xv[j].z * w.z + xv[j].w * w.w;
    }
#pragma unroll
    for (int o = 32; o > 0; o >>= 1) s += __shfl_xor(s, o, 64);
    dots[r] = s;
  }
  if (lane == 0) {
    float lp[4]; float m = -1e30f;
#pragma unroll
    for (int i = 0; i < 4; i++) { lp[i] = dots[i] + lb[i]; m = fmaxf(m, lp[i]); }
    float sum = 0.f;
#pragma unroll
    for (int i = 0; i < 4; i++) { lp[i] = expf(lp[i] - m); sum += lp[i]; }
#pragma unroll
    for (int i = 0; i < 4; i++) lp[i] /= sum;
    float ew[4];
    ew[0] = lp[0] + lp[1]; ew[1] = lp[1] + lp[2]; ew[2] = lp[2] + lp[3]; ew[3] = lp[3];
    float r8[8];
#pragma unroll
    for (int e = 0; e < 8; e++) r8[e] = dots[4 + e] + rb[e] + 0.1f * ew[e & 3];
    int e0 = 0;
#pragma unroll
    for (int e = 1; e < 8; e++) if (r8[e] > r8[e0]) e0 = e;
    int e1 = (e0 == 0) ? 1 : 0;
#pragma unroll
    for (int e = 0; e < 8; e++) if (e != e0 && r8[e] > r8[e1]) e1 = e;
    float tt = expf(r8[e1] - r8[e0]);
    float w0 = 1.f / (1.f + tt);
    float w1 = tt / (1.f + tt);
    top_i[t * 2] = e0; top_i[t * 2 + 1] = e1;
    top_p[t * 2] = w0; top_p[t * 2 + 1] = w1;
    atomicAdd(&counts[e0], 1); atomicAdd(&counts[e1], 1);
  }
}

// ---------------- fused offsets + scatter (single block) ----------------
__global__ void k_offscatter(const int* __restrict__ counts, int* __restrict__ off,
                             const int* __restrict__ top_i, int* cursor,
                             unsigned* __restrict__ list) {
  if (threadIdx.x == 0) {
    int acc = 0;
    for (int e = 0; e < NE; e++) {
      off[e] = acc;
      acc += ((counts[e] + 255) >> 8) << 8;   // pad to 256 (GEMM1 tile M)
    }
    off[NE] = acc;
  }
  __syncthreads();
  for (int t = threadIdx.x; t < T_TOK; t += 1024) {
#pragma unroll
    for (int k = 0; k < 2; k++) {
      int e = top_i[t * 2 + k];
      int pos = atomicAdd(&cursor[e], 1);
      list[off[e] + pos] = (unsigned)(t * 2 + k);
    }
  }
}

// transpose+convert: src f32 [e][K][N] -> dst bf16 [e][N][K]
__global__ void k_transpose_bf16(const float* __restrict__ src, unsigned short* __restrict__ dst,
                                 int K, int N) {
  __shared__ float tile[64][65];
  const float* s = src + (size_t)blockIdx.z * K * N;
  unsigned short* d = dst + (size_t)blockIdx.z * K * N;
  int n0 = blockIdx.x * 64, k0 = blockIdx.y * 64;
  int tr = threadIdx.x >> 4;
  int tc = (threadIdx.x & 15) * 4;
#pragma unroll
  for (int j = 0; j < 4; j++) {
    int row = tr + j * 16;
    float4 v = *(const float4*)&s[(size_t)(k0 + row) * N + n0 + tc];
    tile[row][tc + 0] = v.x; tile[row][tc + 1] = v.y;
    tile[row][tc + 2] = v.z; tile[row][tc + 3] = v.w;
  }
  __syncthreads();
#pragma unroll
  for (int j = 0; j < 4; j++) {
    int n = tr + j * 16;
    union { unsigned short us[4]; uint2 u2; } o;
#pragma unroll
    for (int i = 0; i < 4; i++) o.us[i] = f2bf(tile[tc + i][n]);
    *(uint2*)&d[(size_t)(n0 + n) * K + k0 + tc] = o.u2;
  }
}

__global__ void k_init_out(const int* __restrict__ top_i, const float* __restrict__ top_p,
                           const float* __restrict__ b2, float* __restrict__ out) {
  int i = blockIdx.x * 256 + threadIdx.x;
  int t = i >> 10, d = i & 1023;
  int e0 = top_i[t * 2], e1 = top_i[t * 2 + 1];
  out[i] = top_p[t * 2] * b2[e0 * DM + d] + top_p[t * 2 + 1] * b2[e1 * DM + d];
}

// ---------------- GEMM1: 256x256, BK=64, recipe-exact 2-phase ----------------
// T3 minimum-2-phase: STAGE(t+1) issued FIRST, then ds_read+MFMA of tile t,
// ONE vmcnt(0)+barrier per K-tile (__syncthreads). 8 waves (2Mx4N), acc[8][4],
// 128KB LDS dbuf. A gathered via list; row&7 chunk-XOR swizzle (conflicts 0).
__global__ __launch_bounds__(512, 1) void k_gemm1(
    const unsigned short* __restrict__ Abase,   // xb bf16 [T][DM]
    const unsigned short* __restrict__ Wt,      // w1t bf16 [E][HS][DM]
    const int* __restrict__ off, const unsigned* __restrict__ list,
    const float* __restrict__ bias, unsigned short* __restrict__ Hout) {
  const int K = DM, N = HS, KT = DM / 64;
  int gx = gridDim.x;
  int flat = blockIdx.y * gx + blockIdx.x;
  int cpx = (gx * gridDim.y) >> 3;
  int swz = (flat & 7) * cpx + (flat >> 3);
  int n0 = (swz % gx) * 256;
  int r0 = (swz / gx) * 256;

  int total = off[NE];
  if (r0 >= total) return;
  int e = 0;
  while (r0 >= off[e + 1]) ++e;

  __shared__ __align__(16) unsigned short lA[2][256 * 64];
  __shared__ __align__(16) unsigned short lB[2][256 * 64];

  int tid = threadIdx.x;
  int base = tid >> 3, c8 = tid & 7;          // staging row-base (0..63), chunk
  int koff = (c8 ^ (base & 7)) * 8;           // inverse-swizzled source chunk

  unsigned aOff[4], bOff[4];
#pragma unroll
  for (int l = 0; l < 4; l++) {
    int rowA = l * 64 + base;
    unsigned pair = list[r0 + rowA];
    unsigned arow = (pair == 0xFFFFFFFFu) ? 0u : (pair >> 1);
    aOff[l] = arow * (unsigned)K + (unsigned)koff;
    bOff[l] = (unsigned)(e * N + n0 + rowA) * (unsigned)K + (unsigned)koff;
  }
  int ldsb = base * 64 + c8 * 8;              // ushort idx; load l adds l*4096

  int w = tid >> 6, lane = tid & 63;
  int wm = w >> 2, wn = w & 3;
  int lr = lane & 15, kq = lane >> 4;
  int rsel = lr & 7;

  floatx4 acc[8][4] = {};

#define STAGE1(BUF, TT)                                                       \
  do {                                                                        \
    _Pragma("unroll")                                                         \
    for (int l = 0; l < 4; l++)                                               \
      gload_lds16(Abase + aOff[l] + (TT) * 64, &lA[BUF][l * 4096 + ldsb]);    \
    _Pragma("unroll")                                                         \
    for (int l = 0; l < 4; l++)                                               \
      gload_lds16(Wt + bOff[l] + (TT) * 64, &lB[BUF][l * 4096 + ldsb]);       \
  } while (0)

  STAGE1(0, 0);
  __syncthreads();

  int cur = 0;
  for (int t = 0; t < KT; ++t) {
    if (t + 1 < KT) STAGE1(cur ^ 1, t + 1);   // recipe: stage FIRST, stays in flight
    const short8* qA = (const short8*)lA[cur];
    const short8* qB = (const short8*)lB[cur];
#pragma unroll
    for (int kk = 0; kk < 2; kk++) {
      short8 a[8], b[4];
#pragma unroll
      for (int m = 0; m < 8; m++)
        a[m] = qA[(wm * 128 + m * 16 + lr) * 8 + ((kk * 4 + kq) ^ rsel)];
#pragma unroll
      for (int n = 0; n < 4; n++)
        b[n] = qB[(wn * 64 + n * 16 + lr) * 8 + ((kk * 4 + kq) ^ rsel)];
      __builtin_amdgcn_s_setprio(1);
#pragma unroll
      for (int m = 0; m < 8; m++)
#pragma unroll
        for (int n = 0; n < 4; n++)
          acc[m][n] = __builtin_amdgcn_mfma_f32_16x16x32_bf16(a[m], b[n], acc[m][n], 0, 0, 0);
      __builtin_amdgcn_s_setprio(0);
    }
    __syncthreads();                          // ONE vmcnt(0)+lgkmcnt(0)+barrier per tile
    cur ^= 1;
  }
#undef STAGE1

  float bcol[4];
#pragma unroll
  for (int n = 0; n < 4; n++) bcol[n] = bias[e * N + n0 + wn * 64 + n * 16 + lr];
#pragma unroll
  for (int m = 0; m < 8; m++)
#pragma unroll
    for (int n = 0; n < 4; n++)
#pragma unroll
      for (int g = 0; g < 4; g++) {
        int row = wm * 128 + m * 16 + kq * 4 + g;
        int col = wn * 64 + n * 16 + lr;
        float v = acc[m][n][g] + bcol[n];
        float u = v * (0.7978845608f + 0.0356774081f * v * v);
        float gl = v / (1.f + __expf(-2.f * u));
        Hout[(size_t)(r0 + row) * (size_t)N + n0 + col] = f2bf(gl);
      }
}

// ---------------- GEMM2: 128x128 (best-measured structure, unchanged) ----------------
__global__ __launch_bounds__(256, 4) void k_gemm2(
    const unsigned short* __restrict__ Abase,   // h bf16 [rows][HS]
    const unsigned short* __restrict__ Wt,      // w2t bf16 [E][DM][HS]
    const int* __restrict__ off, const unsigned* __restrict__ list,
    const float* __restrict__ top_p, float* __restrict__ out) {
  const int K = HS, N = DM;
  int nx = gridDim.x;
  int flat = blockIdx.y * nx + blockIdx.x;
  int cpx = (nx * gridDim.y) >> 3;
  int swz = (flat & 7) * cpx + (flat >> 3);
  int n0 = (swz % nx) * 128;
  int r0 = (swz / nx) * 128;

  int total = off[NE];
  if (r0 >= total) return;
  int e = 0;
  while (r0 >= off[e + 1]) ++e;

  __shared__ __align__(16) unsigned short lA[2][128 * 32];
  __shared__ __align__(16) unsigned short lB[2][128 * 32];
  __shared__ float sP[128];
  __shared__ int sTok[128];

  int tid = threadIdx.x;
  int srow = tid >> 2;
  int key_s = (srow >> 1) & 3;
  int koff_src = ((tid & 3) ^ key_s) * 8;
  int kdst = (tid & 3) * 8;

  const unsigned short* srcA[2];
#pragma unroll
  for (int c = 0; c < 2; c++)
    srcA[c] = Abase + (size_t)(r0 + c * 64 + srow) * K + koff_src;
  const unsigned short* srcB[2];
#pragma unroll
  for (int c = 0; c < 2; c++)
    srcB[c] = Wt + ((size_t)e * N + n0 + c * 64 + srow) * K + koff_src;

  if (tid < 128) {
    unsigned pair = list[r0 + tid];
    if (pair == 0xFFFFFFFFu) { sTok[tid] = -1; sP[tid] = 0.f; }
    else { sTok[tid] = (int)(pair >> 1); sP[tid] = top_p[pair]; }
  }

  floatx4 acc[4][4] = {};
  int lane = tid & 63;
  int w = tid >> 6;
  int wm = w >> 1, wn = w & 1;
  int lr = lane & 15, kq = lane >> 4;
  int kx = kq ^ ((lr >> 1) & 3);

#define STAGE2(BUF, KK)                                                       \
  do {                                                                        \
    _Pragma("unroll")                                                         \
    for (int c = 0; c < 2; c++) {                                             \
      gload_lds16(srcA[c] + (KK), &lA[BUF][(c * 64 + srow) * 32 + kdst]);     \
      gload_lds16(srcB[c] + (KK), &lB[BUF][(c * 64 + srow) * 32 + kdst]);     \
    }                                                                         \
  } while (0)

  STAGE2(0, 0);
  __syncthreads();

  int cur = 0;
  for (int k0 = 0; k0 < K; k0 += 32) {
    if (k0 + 32 < K) STAGE2(cur ^ 1, k0 + 32);
    const short8* pA = (const short8*)lA[cur];
    const short8* pB = (const short8*)lB[cur];
    short8 a[4], b[4];
#pragma unroll
    for (int i = 0; i < 4; i++) a[i] = pA[(wm * 64 + i * 16 + lr) * 4 + kx];
#pragma unroll
    for (int j = 0; j < 4; j++) b[j] = pB[(wn * 64 + j * 16 + lr) * 4 + kx];
#pragma unroll
    for (int i = 0; i < 4; i++)
#pragma unroll
      for (int j = 0; j < 4; j++)
        acc[i][j] = __builtin_amdgcn_mfma_f32_16x16x32_bf16(a[i], b[j], acc[i][j], 0, 0, 0);
    __syncthreads();
    cur ^= 1;
  }
#undef STAGE2

  int rbase = wm * 64 + kq * 4;
  int cbase = wn * 64 + lr;
#pragma unroll
  for (int i = 0; i < 4; i++)
#pragma unroll
    for (int j = 0; j < 4; j++)
#pragma unroll
      for (int g = 0; g < 4; g++) {
        int row = rbase + i * 16 + g;
        int col = cbase + j * 16;
        int tok = sTok[row];
        if (tok >= 0)
          atomicAdd(&out[(size_t)tok * DM + n0 + col], sP[row] * acc[i][j][g]);
      }
}

// ---------------- launch ----------------

extern "C" void kernel_launch(void* const* d_in, const int* in_sizes, int n_in,
                              void* d_out, int out_size, void* d_ws, size_t ws_size,
                              hipStream_t stream) {
  const float* x  = (const float*)d_in[0];
  const float* rw = (const float*)d_in[1];
  const float* rb = (const float*)d_in[2];
  const float* lw = (const float*)d_in[3];
  const float* lb = (const float*)d_in[4];
  const float* w1 = (const float*)d_in[5];
  const float* b1 = (const float*)d_in[6];
  const float* w2 = (const float*)d_in[7];
  const float* b2 = (const float*)d_in[8];
  float* out = (float*)d_out;
  char* ws = (char*)d_ws;

  int* counts = (int*)ws;
  int* cursor = (int*)(ws + 32);
  int* off    = (int*)(ws + 64);
  int* top_i  = (int*)(ws + 128);                       // 32 KB
  float* top_p = (float*)(ws + 128 + 32768);            // 32 KB
  unsigned* list = (unsigned*)(ws + 128 + 65536);       // 40 KB
  unsigned short* xb = (unsigned short*)(ws + 131072);                      // 8 MB
  unsigned short* wt = (unsigned short*)(ws + 131072 + 8388608);            // 64 MB (w1t/w2t shared)
  unsigned short* h  = (unsigned short*)(ws + 131072 + 8388608 + 67108864); // 84 MB

  hipMemsetAsync(ws, 0, 128, stream);                   // counts+cursor+off
  hipMemsetAsync(list, 0xFF, MAXROWS * 4, stream);      // sentinel list
  k_cvt_route<<<dim3(T_TOK / 4), dim3(256), 0, stream>>>(
      x, xb, rw, rb, lw, lb, top_i, top_p, counts);
  k_offscatter<<<dim3(1), dim3(1024), 0, stream>>>(counts, off, top_i, cursor, list);
  k_transpose_bf16<<<dim3(HS / 64, DM / 64, NE), dim3(256), 0, stream>>>(w1, wt, DM, HS);
  k_init_out<<<dim3(T_TOK * DM / 256), dim3(256), 0, stream>>>(top_i, top_p, b2, out);
  k_gemm1<<<dim3(HS / 256, MT1), dim3(512), 0, stream>>>(
      xb, wt, off, list, b1, h);
  k_transpose_bf16<<<dim3(DM / 64, HS / 64, NE), dim3(256), 0, stream>>>(w2, wt, HS, DM);
  k_gemm2<<<dim3(DM / 128, MT2), dim3(256), 0, stream>>>(
      h, wt, off, list, top_p, out);
}

// Round 10
// 523.794 us; speedup vs baseline: 1.2066x; 1.0289x over previous
//
#include <hip/hip_runtime.h>
#include <cstdint>
#include <cstddef>

#define T_TOK 4096
#define DM 1024
#define HS 4096
#define NE 8
#define MAXROWS 9216   // 8192 pairs + 8*128 padding worst case
#define MAXTILES 72    // MAXROWS/128

typedef __attribute__((ext_vector_type(8))) short short8;
typedef __attribute__((ext_vector_type(4))) float floatx4;

__device__ __forceinline__ unsigned short f2bf(float f) {
  union { float f; unsigned u; } v; v.f = f;
  unsigned r = (v.u + 0x7fffu + ((v.u >> 16) & 1u)) >> 16;
  return (unsigned short)r;
}

__device__ __forceinline__ void gload_lds16(const void* g, void* l) {
  __builtin_amdgcn_global_load_lds((const __attribute__((address_space(1))) void*)g,
                                   (__attribute__((address_space(3))) void*)l, 16, 0, 0);
}

// ---------------- fused cvt(x->bf16) + routing ----------------
__global__ void k_cvt_route(const float* __restrict__ x, unsigned short* __restrict__ xb,
                            const float* __restrict__ rw, const float* __restrict__ rb,
                            const float* __restrict__ lw, const float* __restrict__ lb,
                            int* __restrict__ top_i, float* __restrict__ top_p,
                            int* __restrict__ counts) {
#pragma unroll
  for (int j = 0; j < 4; j++) {
    int i = blockIdx.x * 1024 + j * 256 + threadIdx.x;
    float4 v = ((const float4*)x)[i];
    union { unsigned short us[4]; uint2 u2; } o;
    o.us[0] = f2bf(v.x); o.us[1] = f2bf(v.y); o.us[2] = f2bf(v.z); o.us[3] = f2bf(v.w);
    ((uint2*)xb)[i] = o.u2;
  }
  int t = blockIdx.x * 4 + (threadIdx.x >> 6);
  int lane = threadIdx.x & 63;
  const float4* xt = (const float4*)(x + (size_t)t * DM);
  float4 xv[4];
#pragma unroll
  for (int j = 0; j < 4; j++) xv[j] = xt[lane * 4 + j];
  float dots[12];
#pragma unroll
  for (int r = 0; r < 12; r++) {
    const float4* wr = (const float4*)(r < 4 ? lw + r * DM : rw + (r - 4) * DM);
    float s = 0.f;
#pragma unroll
    for (int j = 0; j < 4; j++) {
      float4 w = wr[lane * 4 + j];
      s += xv[j].x * w.x + xv[j].y * w.y + xv[j].z * w.z + xv[j].w * w.w;
    }
#pragma unroll
    for (int o = 32; o > 0; o >>= 1) s += __shfl_xor(s, o, 64);
    dots[r] = s;
  }
  if (lane == 0) {
    float lp[4]; float m = -1e30f;
#pragma unroll
    for (int i = 0; i < 4; i++) { lp[i] = dots[i] + lb[i]; m = fmaxf(m, lp[i]); }
    float sum = 0.f;
#pragma unroll
    for (int i = 0; i < 4; i++) { lp[i] = expf(lp[i] - m); sum += lp[i]; }
#pragma unroll
    for (int i = 0; i < 4; i++) lp[i] /= sum;
    float ew[4];
    ew[0] = lp[0] + lp[1]; ew[1] = lp[1] + lp[2]; ew[2] = lp[2] + lp[3]; ew[3] = lp[3];
    float r8[8];
#pragma unroll
    for (int e = 0; e < 8; e++) r8[e] = dots[4 + e] + rb[e] + 0.1f * ew[e & 3];
    int e0 = 0;
#pragma unroll
    for (int e = 1; e < 8; e++) if (r8[e] > r8[e0]) e0 = e;
    int e1 = (e0 == 0) ? 1 : 0;
#pragma unroll
    for (int e = 0; e < 8; e++) if (e != e0 && r8[e] > r8[e1]) e1 = e;
    float tt = expf(r8[e1] - r8[e0]);
    float w0 = 1.f / (1.f + tt);
    float w1 = tt / (1.f + tt);
    top_i[t * 2] = e0; top_i[t * 2 + 1] = e1;
    top_p[t * 2] = w0; top_p[t * 2 + 1] = w1;
    atomicAdd(&counts[e0], 1); atomicAdd(&counts[e1], 1);
  }
}

// ---------------- fused offsets + scatter (single block) ----------------
__global__ void k_offscatter(const int* __restrict__ counts, int* __restrict__ off,
                             const int* __restrict__ top_i, int* cursor,
                             unsigned* __restrict__ list) {
  if (threadIdx.x == 0) {
    int acc = 0;
    for (int e = 0; e < NE; e++) {
      off[e] = acc;
      acc += ((counts[e] + 127) >> 7) << 7;   // pad to 128 (GEMM tile M)
    }
    off[NE] = acc;
  }
  __syncthreads();
  for (int t = threadIdx.x; t < T_TOK; t += 1024) {
#pragma unroll
    for (int k = 0; k < 2; k++) {
      int e = top_i[t * 2 + k];
      int pos = atomicAdd(&cursor[e], 1);
      list[off[e] + pos] = (unsigned)(t * 2 + k);
    }
  }
}

// ---------------- transpose v2: src f32 [e][K][N] -> dst bf16 [e][N][K] ----------------
// 128k x 128n tiles: 512B read segments, 256B write segments (vs 256/128 before).
// LDS stores bf16 k-pairs packed in u32, columns XOR-swizzled on bits 2-5
// (preserves 4-u32 runs for b128 reads). 34KB LDS -> 4 blocks/CU.
template <int K, int N>
__global__ __launch_bounds__(256) void k_transpose2(const float* __restrict__ src,
                                                    unsigned short* __restrict__ dst) {
  __shared__ unsigned tile[128][68];   // [n][k-pair^swz]
  const float* s = src + (size_t)blockIdx.z * K * N;
  unsigned short* d = dst + (size_t)blockIdx.z * K * N;
  int n0 = blockIdx.x * 128, k0 = blockIdx.y * 128;
  int tid = threadIdx.x;
  int nc4 = (tid & 31) * 4;            // 4 consecutive n
  int kg = tid >> 5;                   // 0..7
#pragma unroll
  for (int j = 0; j < 8; j++) {
    int kp = kg + 8 * j;               // k-pair index 0..63
    int k = 2 * kp;
    float4 a = *(const float4*)&s[(size_t)(k0 + k) * N + n0 + nc4];
    float4 b = *(const float4*)&s[(size_t)(k0 + k + 1) * N + n0 + nc4];
    const float* fa = (const float*)&a;
    const float* fb = (const float*)&b;
#pragma unroll
    for (int i = 0; i < 4; i++) {
      int n = nc4 + i;
      int v = ((n >> 3) & 15) << 2;
      tile[n][kp ^ v] = (unsigned)f2bf(fa[i]) | ((unsigned)f2bf(fb[i]) << 16);
    }
  }
  __syncthreads();
  int h = tid & 15;                    // k-chunk: 4 u32 = 8 bf16
#pragma unroll
  for (int j = 0; j < 8; j++) {
    int n = (tid >> 4) + 16 * j;
    int v = ((n >> 3) & 15) << 2;
    uint4 q = *(const uint4*)&tile[n][(4 * h) ^ v];
    *(uint4*)&d[(size_t)(n0 + n) * K + k0 + 8 * h] = q;
  }
}

__global__ void k_init_out(const int* __restrict__ top_i, const float* __restrict__ top_p,
                           const float* __restrict__ b2, float4* __restrict__ out) {
  int i = blockIdx.x * 256 + threadIdx.x;   // float4 index
  int t = i >> 8, d4 = i & 255;             // 256 float4 per token
  int e0 = top_i[t * 2], e1 = top_i[t * 2 + 1];
  float p0 = top_p[t * 2], p1 = top_p[t * 2 + 1];
  float4 b0 = ((const float4*)(b2 + e0 * DM))[d4];
  float4 b1 = ((const float4*)(b2 + e1 * DM))[d4];
  out[i] = make_float4(p0 * b0.x + p1 * b1.x, p0 * b0.y + p1 * b1.y,
                       p0 * b0.z + p1 * b1.z, p0 * b0.w + p1 * b1.w);
}

// ---------------- grouped GEMM (round-7 proven structure, best measured) ----------------
template <int MODE>
__global__ __launch_bounds__(256, 4) void k_gemm(
    const unsigned short* __restrict__ Abase,
    const unsigned short* __restrict__ Wt,   // [E][N][K] bf16
    const int* __restrict__ off, const unsigned* __restrict__ list,
    const float* __restrict__ bias, const float* __restrict__ top_p,
    unsigned short* __restrict__ Hout, float* __restrict__ out,
    int K, int N) {
  int nx = gridDim.x;
  int flat = blockIdx.y * nx + blockIdx.x;
  int cpx = (nx * gridDim.y) >> 3;
  int swz = (flat & 7) * cpx + (flat >> 3);
  int n0 = (swz % nx) * 128;
  int r0 = (swz / nx) * 128;

  int total = off[NE];
  if (r0 >= total) return;
  int e = 0;
  while (r0 >= off[e + 1]) ++e;

  __shared__ __align__(16) unsigned short lA[2][128 * 32];
  __shared__ __align__(16) unsigned short lB[2][128 * 32];
  __shared__ float sP[128];
  __shared__ int sTok[128];

  int tid = threadIdx.x;
  int srow = tid >> 2;
  int key_s = (srow >> 1) & 3;
  int koff_src = ((tid & 3) ^ key_s) * 8;
  int kdst = (tid & 3) * 8;

  const unsigned short* srcA[2];
#pragma unroll
  for (int c = 0; c < 2; c++) {
    int row = c * 64 + srow;
    size_t arow;
    if (MODE == 0) {
      unsigned pair = list[r0 + row];
      arow = (pair == 0xFFFFFFFFu) ? 0 : (size_t)(pair >> 1);
    } else {
      arow = (size_t)(r0 + row);
    }
    srcA[c] = Abase + arow * K + koff_src;
  }
  const unsigned short* srcB[2];
#pragma unroll
  for (int c = 0; c < 2; c++)
    srcB[c] = Wt + ((size_t)e * N + n0 + c * 64 + srow) * K + koff_src;

  if (MODE == 1 && tid < 128) {
    unsigned pair = list[r0 + tid];
    if (pair == 0xFFFFFFFFu) { sTok[tid] = -1; sP[tid] = 0.f; }
    else { sTok[tid] = (int)(pair >> 1); sP[tid] = top_p[pair]; }
  }

  floatx4 acc[4][4] = {};
  int lane = tid & 63;
  int w = tid >> 6;
  int wm = w >> 1, wn = w & 1;
  int lr = lane & 15, kq = lane >> 4;
  int kx = kq ^ ((lr >> 1) & 3);

#define STAGE(BUF, KK)                                                        \
  do {                                                                        \
    _Pragma("unroll")                                                         \
    for (int c = 0; c < 2; c++) {                                             \
      gload_lds16(srcA[c] + (KK), &lA[BUF][(c * 64 + srow) * 32 + kdst]);     \
      gload_lds16(srcB[c] + (KK), &lB[BUF][(c * 64 + srow) * 32 + kdst]);     \
    }                                                                         \
  } while (0)

  STAGE(0, 0);
  __syncthreads();

  int cur = 0;
  for (int k0 = 0; k0 < K; k0 += 32) {
    if (k0 + 32 < K) STAGE(cur ^ 1, k0 + 32);
    const short8* pA = (const short8*)lA[cur];
    const short8* pB = (const short8*)lB[cur];
    short8 a[4], b[4];
#pragma unroll
    for (int i = 0; i < 4; i++) a[i] = pA[(wm * 64 + i * 16 + lr) * 4 + kx];
#pragma unroll
    for (int j = 0; j < 4; j++) b[j] = pB[(wn * 64 + j * 16 + lr) * 4 + kx];
#pragma unroll
    for (int i = 0; i < 4; i++)
#pragma unroll
      for (int j = 0; j < 4; j++)
        acc[i][j] = __builtin_amdgcn_mfma_f32_16x16x32_bf16(a[i], b[j], acc[i][j], 0, 0, 0);
    __syncthreads();
    cur ^= 1;
  }
#undef STAGE

  int rbase = wm * 64 + kq * 4;
  int cbase = wn * 64 + lr;
  if (MODE == 0) {
#pragma unroll
    for (int i = 0; i < 4; i++)
#pragma unroll
      for (int j = 0; j < 4; j++)
#pragma unroll
        for (int g = 0; g < 4; g++) {
          int row = rbase + i * 16 + g;
          int col = cbase + j * 16;
          float v = acc[i][j][g] + bias[e * N + n0 + col];
          float u = v * (0.7978845608f + 0.0356774081f * v * v);
          float gl = v / (1.f + __expf(-2.f * u));
          Hout[(size_t)(r0 + row) * (size_t)N + n0 + col] = f2bf(gl);
        }
  } else {
#pragma unroll
    for (int i = 0; i < 4; i++)
#pragma unroll
      for (int j = 0; j < 4; j++)
#pragma unroll
        for (int g = 0; g < 4; g++) {
          int row = rbase + i * 16 + g;
          int col = cbase + j * 16;
          int tok = sTok[row];
          if (tok >= 0)
            atomicAdd(&out[(size_t)tok * DM + n0 + col], sP[row] * acc[i][j][g]);
        }
  }
}

// ---------------- launch ----------------

extern "C" void kernel_launch(void* const* d_in, const int* in_sizes, int n_in,
                              void* d_out, int out_size, void* d_ws, size_t ws_size,
                              hipStream_t stream) {
  const float* x  = (const float*)d_in[0];
  const float* rw = (const float*)d_in[1];
  const float* rb = (const float*)d_in[2];
  const float* lw = (const float*)d_in[3];
  const float* lb = (const float*)d_in[4];
  const float* w1 = (const float*)d_in[5];
  const float* b1 = (const float*)d_in[6];
  const float* w2 = (const float*)d_in[7];
  const float* b2 = (const float*)d_in[8];
  float* out = (float*)d_out;
  char* ws = (char*)d_ws;

  int* counts = (int*)ws;
  int* cursor = (int*)(ws + 32);
  int* off    = (int*)(ws + 64);
  int* top_i  = (int*)(ws + 128);                       // 32 KB
  float* top_p = (float*)(ws + 128 + 32768);            // 32 KB
  unsigned* list = (unsigned*)(ws + 128 + 65536);       // 36 KB
  unsigned short* xb = (unsigned short*)(ws + 131072);                      // 8 MB
  unsigned short* wt = (unsigned short*)(ws + 131072 + 8388608);            // 64 MB (w1t/w2t shared)
  unsigned short* h  = (unsigned short*)(ws + 131072 + 8388608 + 67108864); // 76 MB

  hipMemsetAsync(ws, 0, 128, stream);                   // counts+cursor+off
  hipMemsetAsync(list, 0xFF, MAXROWS * 4, stream);      // sentinel list
  k_cvt_route<<<dim3(T_TOK / 4), dim3(256), 0, stream>>>(
      x, xb, rw, rb, lw, lb, top_i, top_p, counts);
  k_offscatter<<<dim3(1), dim3(1024), 0, stream>>>(counts, off, top_i, cursor, list);
  k_transpose2<DM, HS><<<dim3(HS / 128, DM / 128, NE), dim3(256), 0, stream>>>(w1, wt);
  k_init_out<<<dim3(T_TOK * DM / 4 / 256), dim3(256), 0, stream>>>(
      top_i, top_p, b2, (float4*)out);
  k_gemm<0><<<dim3(HS / 128, MAXTILES), dim3(256), 0, stream>>>(
      xb, wt, off, list, b1, top_p, h, nullptr, DM, HS);
  k_transpose2<HS, DM><<<dim3(DM / 128, HS / 128, NE), dim3(256), 0, stream>>>(w2, wt);
  k_gemm<1><<<dim3(DM / 128, MAXTILES), dim3(256), 0, stream>>>(
      h, wt, off, list, nullptr, top_p, nullptr, out, HS, DM);
}